// Round 20
// baseline (45.022 us; speedup 1.0000x reference)
//
#include <hip/hip_runtime.h>
#include <cstddef>

#define NB 64
#define NP 8732
#define NM 16
#define NC 21
#define PSPLIT 16
#define CH 546            // ceil(NP/PSPLIT)
#define SSPL 35           // k_loss: 1 prior/thread, ceil(NP/256) chunks
#define TKT 1024          // k_topk threads (R20: was 512)
#define NKEY3 9           // ceil(NP/TKT) keys per thread

typedef float f32x4 __attribute__((ext_vector_type(4), aligned(4)));

// CLASS_W: base 1.0; [3,4,5,9,10,11,16,17,18]=2.5; [15,7,12,8]=0.75; [0]=0.5
__constant__ float c_w[NC] = {
    0.5f, 1.0f, 1.0f, 2.5f, 2.5f, 2.5f, 1.0f, 0.75f, 0.75f, 2.5f, 2.5f,
    2.5f, 0.75f, 1.0f, 1.0f, 0.75f, 2.5f, 2.5f, 2.5f, 1.0f, 1.0f};

// ------------- Kernel 1: transposed per-truth argmax, division-free (R17) -------------
__global__ __launch_bounds__(256) void k_argmax(
    const float4* __restrict__ defaults, const float4* __restrict__ gtb,
    float* __restrict__ pbin, float* __restrict__ pbun, int* __restrict__ pbi)
{
    const int b = blockIdx.x, s = blockIdx.y, t = threadIdx.x;
    const int lane = t & 63, wv = t >> 6;
    __shared__ float4 s_def[CH];
    __shared__ float s_t0[NM], s_t1[NM], s_t2[NM], s_t3[NM], s_area[NM];
    __shared__ float s_ri[NM][4], s_ru[NM][4];
    __shared__ int   s_rx[NM][4];

    if (t < NM) {
        float4 g = gtb[b * NM + t];
        s_t0[t] = g.x; s_t1[t] = g.y; s_t2[t] = g.z; s_t3[t] = g.w;
        s_area[t] = (g.z - g.x) * (g.w - g.y);
    }
    const int pbase = s * CH;
    const int cnt = min(NP - pbase, CH);
    for (int i = t; i < cnt; i += 256)
        s_def[i] = defaults[pbase + i];
    __syncthreads();

    const int j = t & 15;
    const int sub = t >> 4;
    const float g0 = s_t0[j], g1 = s_t1[j], g2 = s_t2[j], g3 = s_t3[j], ga = s_area[j];

    float bi = -1.0f, bu = 1.0f; int bx = 0x7fffffff;
    for (int i = sub; i < cnt; i += 16) {        // ascending p: strict > keeps smallest
        float4 d = s_def[i];
        float a1 = (d.z - d.x) * (d.w - d.y);
        float w = fminf(d.z, g2) - fmaxf(d.x, g0);
        float h = fminf(d.w, g3) - fmaxf(d.y, g1);
        w = fmaxf(w, 0.0f); h = fmaxf(h, 0.0f);
        float inter = w * h;
        float uni = a1 + ga - inter;
        if (inter * bu > bi * uni) { bi = inter; bu = uni; bx = pbase + i; }
    }

    #pragma unroll
    for (int off = 16; off <= 32; off <<= 1) {
        float i2 = __shfl_xor(bi, off);
        float u2 = __shfl_xor(bu, off);
        int   x2 = __shfl_xor(bx, off);
        float a = i2 * bu, c = bi * u2;
        if (a > c || (a == c && x2 < bx)) { bi = i2; bu = u2; bx = x2; }
    }
    if (lane < NM) { s_ri[lane][wv] = bi; s_ru[lane][wv] = bu; s_rx[lane][wv] = bx; }
    __syncthreads();
    if (t < NM) {
        float vi = s_ri[t][0], vu = s_ru[t][0]; int x = s_rx[t][0];
        #pragma unroll
        for (int w = 1; w < 4; w++) {
            float i2 = s_ri[t][w], u2 = s_ru[t][w]; int x2 = s_rx[t][w];
            float a = i2 * vu, c = vi * u2;
            if (a > c || (a == c && x2 < x)) { vi = i2; vu = u2; x = x2; }
        }
        pbin[(b * PSPLIT + s) * NM + t] = vi;
        pbun[(b * PSPLIT + s) * NM + t] = vu;
        pbi [(b * PSPLIT + s) * NM + t] = x;
    }
}

// ------- Kernel 2: fused match-resolve + losses; div-free IoU + no-max softmax (R19) -------
__global__ __launch_bounds__(256) void k_loss(
    const float4* __restrict__ loc, const float* __restrict__ conf,
    const float* __restrict__ cent, const float4* __restrict__ defaults,
    const float4* __restrict__ gtb, const int* __restrict__ gtl,
    const float* __restrict__ pbin, const float* __restrict__ pbun,
    const int* __restrict__ pbi,
    float* __restrict__ lossc,
    int* __restrict__ nposP, float* __restrict__ locP,
    float* __restrict__ centP, float* __restrict__ pfocP)
{
    const int b = blockIdx.x, s = blockIdx.y, t = threadIdx.x;
    __shared__ float s_t0[NM], s_t1[NM], s_t2[NM], s_t3[NM], s_area[NM];
    __shared__ int s_lab[NM], s_ovp[NM];
    if (t < NM) {
        float4 g = gtb[b * NM + t];
        s_t0[t] = g.x; s_t1[t] = g.y; s_t2[t] = g.z; s_t3[t] = g.w;
        s_area[t] = (g.z - g.x) * (g.w - g.y);
        s_lab[t] = gtl[b * NM + t];
        float vi = -2.0f, vu = 1.0f; int x = 0x7fffffff;
        for (int c = 0; c < PSPLIT; c++) {
            float i2 = pbin[(b * PSPLIT + c) * NM + t];
            float u2 = pbun[(b * PSPLIT + c) * NM + t];
            int   x2 = pbi [(b * PSPLIT + c) * NM + t];
            float a = i2 * vu, cc = vi * u2;
            if (a > cc || (a == cc && x2 < x)) { vi = i2; vu = u2; x = x2; }
        }
        s_ovp[t] = x;
    }
    __syncthreads();

    float locS = 0.0f, centS = 0.0f, pfocS = 0.0f; int np = 0;

    const int p = s * 256 + t;
    if (p < NP) {
        const float* cp = conf + ((size_t)b * NP + p) * NC;
        f32x4 v0 = *(const f32x4*)(cp + 0);
        f32x4 v1 = *(const f32x4*)(cp + 4);
        f32x4 v2 = *(const f32x4*)(cp + 8);
        f32x4 v3 = *(const f32x4*)(cp + 12);
        f32x4 v4 = *(const f32x4*)(cp + 16);
        float c20 = cp[20];

        float4 d = defaults[p];
        float a1 = (d.z - d.x) * (d.w - d.y);
        float bi = -1.0f, bu = 1.0f; int bj = 0;
        #pragma unroll
        for (int j = 0; j < NM; j++) {
            float w2 = fminf(d.z, s_t2[j]) - fmaxf(d.x, s_t0[j]);
            float h2 = fminf(d.w, s_t3[j]) - fmaxf(d.y, s_t1[j]);
            w2 = fmaxf(w2, 0.0f); h2 = fmaxf(h2, 0.0f);
            float inter = w2 * h2;
            float uni = a1 + s_area[j] - inter;
            if (inter * bu > bi * uni) { bi = inter; bu = uni; bj = j; }  // first-occurrence
        }
        bool ovr = false;
        #pragma unroll
        for (int j = NM - 1; j >= 0; j--) {       // later j wins (ref override loop)
            if (s_ovp[j] == p) { bj = j; ovr = true; break; }
        }
        int lab = (!ovr && 2.0f * bi < bu) ? 0 : s_lab[bj];
        bool pos = lab > 0;

        float se = __expf(v0.x) + __expf(v0.y) + __expf(v0.z) + __expf(v0.w)
                 + __expf(v1.x) + __expf(v1.y) + __expf(v1.z) + __expf(v1.w)
                 + __expf(v2.x) + __expf(v2.y) + __expf(v2.z) + __expf(v2.w)
                 + __expf(v3.x) + __expf(v3.y) + __expf(v3.z) + __expf(v3.w)
                 + __expf(v4.x) + __expf(v4.y) + __expf(v4.z) + __expf(v4.w)
                 + __expf(c20);
        f32x4 va = (lab < 8) ? ((lab < 4) ? v0 : v1)
                             : ((lab < 12) ? v2 : ((lab < 16) ? v3 : v4));
        int li = lab & 3;
        float cl = (li < 2) ? ((li == 0) ? va.x : va.y) : ((li == 2) ? va.z : va.w);
        cl = (lab == 20) ? c20 : cl;

        float logpt = cl - __logf(se);
        float ce = -logpt;
        float pt = __expf(logpt);
        float omp = 1.0f - pt;
        float focal = 0.25f * omp * omp * c_w[lab] * ce;

        lossc[(size_t)b * NP + p] = pos ? 0.0f : focal;

        if (pos) {
            float g0 = s_t0[bj], g1 = s_t1[bj], g2 = s_t2[bj], g3 = s_t3[bj];
            float dw = d.z - d.x, dh = d.w - d.y;
            float gw = g2 - g0,  gh = g3 - g1;
            float dcx = d.x + dw * 0.5f, dcy = d.y + dh * 0.5f;
            float gcx = g0 + gw * 0.5f,  gcy = g1 + gh * 0.5f;
            float e0 = (gcx - dcx) / (dw * 0.1f + 1e-8f);
            float e1 = (gcy - dcy) / (dh * 0.1f + 1e-8f);
            float e2 = logf(gw / (dw + 1e-8f) + 1e-8f) / 0.1f;
            float e3 = logf(gh / (dh + 1e-8f) + 1e-8f) / 0.1f;
            float4 lp = loc[(size_t)b * NP + p];
            float a, sl = 0.0f;
            a = fabsf(lp.x - e0); sl += (a < 1.0f) ? 0.5f * a * a : a - 0.5f;
            a = fabsf(lp.y - e1); sl += (a < 1.0f) ? 0.5f * a * a : a - 0.5f;
            a = fabsf(lp.z - e2); sl += (a < 1.0f) ? 0.5f * a * a : a - 0.5f;
            a = fabsf(lp.w - e3); sl += (a < 1.0f) ? 0.5f * a * a : a - 0.5f;
            locS += sl;

            float ccx = (g0 + g2) * 0.5f, ccy = (g1 + g3) * 0.5f;
            float ld = ccx - g0, rd = g2 - ccx, td = ccy - g1, bd = g3 - ccy;
            float centT = sqrtf((fminf(ld, rd) / fmaxf(ld, rd + 1e-8f)) *
                                (fminf(td, bd) / fmaxf(td, bd + 1e-8f)));
            float x = cent[(size_t)b * NP + p];
            float bce = fmaxf(x, 0.0f) - x * centT + log1pf(expf(-fabsf(x)));
            centS += bce;
            pfocS += focal;
            np++;
        }
    }

    const int lane = t & 63, wv = t >> 6;
    float fnp = (float)np;
    #pragma unroll
    for (int off = 32; off > 0; off >>= 1) {
        locS  += __shfl_down(locS,  off);
        centS += __shfl_down(centS, off);
        pfocS += __shfl_down(pfocS, off);
        fnp   += __shfl_down(fnp,   off);
    }
    __shared__ float r0[4], r1[4], r2[4], r3[4];
    if (lane == 0) { r0[wv] = locS; r1[wv] = centS; r2[wv] = pfocS; r3[wv] = fnp; }
    __syncthreads();
    if (t == 0) {
        int idx = b * SSPL + s;
        locP[idx]  = r0[0] + r0[1] + r0[2] + r0[3];
        centP[idx] = r1[0] + r1[1] + r1[2] + r1[3];
        pfocP[idx] = r2[0] + r2[1] + r2[2] + r2[3];
        nposP[idx] = (int)(r3[0] + r3[1] + r3[2] + r3[3]);
    }
}

// ------- Kernel 3: per-batch top-k, 1024 threads (R20: halves per-thread serial work) -------
__global__ __launch_bounds__(TKT) void k_topk(
    const float* __restrict__ lossc, const int* __restrict__ nposP,
    const float* __restrict__ locP, const float* __restrict__ centP,
    const float* __restrict__ pfocP,
    float* __restrict__ locB, float* __restrict__ centB, float* __restrict__ pfocB,
    int* __restrict__ nposB, float* __restrict__ topkB, float* __restrict__ selcB)
{
    const int b = blockIdx.x, t = threadIdx.x;
    const int lane = t & 63, wvi = t >> 6;   // 16 waves
    __shared__ unsigned s_hist[2048];
    __shared__ unsigned s_ws[16];
    __shared__ unsigned s_selB, s_selC;
    __shared__ float s_pf[3];
    __shared__ unsigned s_npb;
    __shared__ int   s_ci[16];
    __shared__ float s_sf[16];

    unsigned ukey[NKEY3];
    #pragma unroll
    for (int i = 0; i < NKEY3; i++) {
        int p = i * TKT + t;
        ukey[i] = (p < NP) ? __float_as_uint(lossc[(size_t)b * NP + p]) : 0u;
    }

    if (wvi == 0) {
        float lB = 0.0f, cB = 0.0f, fB = 0.0f; unsigned nB = 0;
        if (lane < SSPL) {
            int i = b * SSPL + lane;
            lB = locP[i]; cB = centP[i]; fB = pfocP[i]; nB = (unsigned)nposP[i];
        }
        #pragma unroll
        for (int off = 32; off > 0; off >>= 1) {
            lB += __shfl_down(lB, off); cB += __shfl_down(cB, off);
            fB += __shfl_down(fB, off); nB += __shfl_down(nB, off);
        }
        if (lane == 0) { s_pf[0] = lB; s_pf[1] = cB; s_pf[2] = fB; s_npb = nB; }
    }
    __syncthreads();
    const int npb = (int)s_npb;
    const int k = min(3 * npb, NP - 1);

    unsigned vk = 0;
    if (k > 0) {
        unsigned carried = 0;
        #pragma unroll
        for (int pass = 0; pass < 3; pass++) {
            const int lo   = (pass == 0) ? 20 : (pass == 1) ? 9 : 0;
            const int bits = (pass == 2) ? 9 : 11;
            const int nb   = 1 << bits;
            const int bpt  = (nb + TKT - 1) / TKT;   // bins/thread: 2, 2, 1
            const unsigned himask = (pass == 0) ? 0u : (0xFFFFFFFFu << (lo + bits));

            for (int z = t; z < nb; z += TKT) s_hist[z] = 0;
            __syncthreads();

            #pragma unroll
            for (int i = 0; i < NKEY3; i++) {
                unsigned kk = ukey[i];
                if ((kk & himask) == (vk & himask))
                    atomicAdd(&s_hist[(kk >> lo) & (nb - 1)], 1u);
            }
            __syncthreads();

            unsigned h[2]; unsigned tot = 0;
            #pragma unroll
            for (int j = 0; j < 2; j++) {
                int bidx = t * bpt + j;
                h[j] = (j < bpt && bidx < nb) ? s_hist[bidx] : 0u;
                tot += h[j];
            }
            unsigned suf = tot;   // inclusive suffix within wave (lane..63)
            #pragma unroll
            for (int off = 1; off < 64; off <<= 1) {
                unsigned o = __shfl_down(suf, off);
                if (lane + off < 64) suf += o;
            }
            if (lane == 0) s_ws[wvi] = suf;
            __syncthreads();
            unsigned aw = 0;
            for (int w = wvi + 1; w < 16; w++) aw += s_ws[w];
            unsigned acc = aw + (suf - tot);   // count in bins strictly above my chunk
            #pragma unroll
            for (int j = 1; j >= 0; j--) {
                int bidx = t * bpt + j;
                if (j < bpt && bidx < nb) {
                    if (carried + acc < (unsigned)k &&
                        (unsigned)k <= carried + acc + h[j]) {
                        s_selB = (unsigned)bidx;
                        s_selC = carried + acc;
                    }
                    acc += h[j];
                }
            }
            __syncthreads();
            vk |= s_selB << lo;
            carried = s_selC;
            __syncthreads();
        }
    }

    int cgt = 0; float sgt = 0.0f;
    #pragma unroll
    for (int i = 0; i < NKEY3; i++) {
        unsigned kk = ukey[i];
        if (kk > vk) { cgt++; sgt += __uint_as_float(kk); }
    }
    #pragma unroll
    for (int off = 32; off > 0; off >>= 1) {
        cgt += __shfl_down(cgt, off);
        sgt += __shfl_down(sgt, off);
    }
    if (lane == 0) { s_ci[wvi] = cgt; s_sf[wvi] = sgt; }
    __syncthreads();
    if (t == 0) {
        int tc = 0; float ts = 0.0f;
        #pragma unroll
        for (int w = 0; w < 16; w++) { tc += s_ci[w]; ts += s_sf[w]; }
        locB[b] = s_pf[0]; centB[b] = s_pf[1]; pfocB[b] = s_pf[2];
        nposB[b] = npb;
        topkB[b] = (k > 0) ? (ts + (float)(k - tc) * __uint_as_float(vk)) : 0.0f;
        selcB[b] = (float)(npb + k);
    }
}

// ---------------- Kernel 4: final combine ----------------
__global__ __launch_bounds__(64) void k_final(
    const float* __restrict__ locB, const float* __restrict__ centB,
    const float* __restrict__ pfocB, const int* __restrict__ nposB,
    const float* __restrict__ topkB, const float* __restrict__ selcB,
    float* __restrict__ out)
{
    const int t = threadIdx.x;
    float l = locB[t], c = centB[t], pf = pfocB[t];
    float npf = (float)nposB[t], tk = topkB[t], sc = selcB[t];
    #pragma unroll
    for (int off = 32; off > 0; off >>= 1) {
        l   += __shfl_down(l,   off);
        c   += __shfl_down(c,   off);
        pf  += __shfl_down(pf,  off);
        npf += __shfl_down(npf, off);
        tk  += __shfl_down(tk,  off);
        sc  += __shfl_down(sc,  off);
    }
    if (t == 0)
        out[0] = 2.0f * (l / npf) + (pf + tk) / sc + (c / npf);
}

extern "C" void kernel_launch(void* const* d_in, const int* in_sizes, int n_in,
                              void* d_out, int out_size, void* d_ws, size_t ws_size,
                              hipStream_t stream) {
    const float4* loc      = (const float4*)d_in[0];
    const float*  conf     = (const float*)d_in[1];
    const float*  cent     = (const float*)d_in[2];
    const float4* defaults = (const float4*)d_in[3];
    const float4* gtb      = (const float4*)d_in[4];
    const int*    gtl      = (const int*)d_in[5];
    float* out = (float*)d_out;

    const size_t BP = (size_t)NB * NP;
    const int NT = NB * SSPL;   // 2240 loss tiles
    char* q = (char*)d_ws;
    float* lossc = (float*)q;  q += BP * 4;
    int*   nposP = (int*)q;    q += NT * 4;
    float* locP  = (float*)q;  q += NT * 4;
    float* centP = (float*)q;  q += NT * 4;
    float* pfocP = (float*)q;  q += NT * 4;
    float* locB  = (float*)q;  q += NB * 4;
    float* centB = (float*)q;  q += NB * 4;
    float* pfocB = (float*)q;  q += NB * 4;
    int*   nposB = (int*)q;    q += NB * 4;
    float* topkB = (float*)q;  q += NB * 4;
    float* selcB = (float*)q;  q += NB * 4;
    float* pbin  = (float*)q;  q += (size_t)NB * PSPLIT * NM * 4;
    float* pbun  = (float*)q;  q += (size_t)NB * PSPLIT * NM * 4;
    int*   pbi   = (int*)q;

    k_argmax<<<dim3(NB, PSPLIT), 256, 0, stream>>>(defaults, gtb, pbin, pbun, pbi);
    k_loss<<<dim3(NB, SSPL), 256, 0, stream>>>(loc, conf, cent, defaults, gtb, gtl,
                                               pbin, pbun, pbi, lossc,
                                               nposP, locP, centP, pfocP);
    k_topk<<<NB, TKT, 0, stream>>>(lossc, nposP, locP, centP, pfocP,
                                   locB, centB, pfocB, nposB, topkB, selcB);
    k_final<<<1, 64, 0, stream>>>(locB, centB, pfocB, nposB, topkB, selcB, out);
}

// Round 21
// 43.526 us; speedup vs baseline: 1.0344x; 1.0344x over previous
//
#include <hip/hip_runtime.h>
#include <cstddef>

#define NB 64
#define NP 8732
#define NM 16
#define NC 21
#define PSPLIT 16
#define CH 546            // ceil(NP/PSPLIT)
#define SSPL 35           // k_loss: 1 prior/thread, ceil(NP/256) chunks
#define NKEY2 18          // ceil(NP/512) keys per thread in k_topk

typedef float f32x4 __attribute__((ext_vector_type(4), aligned(4)));

// CLASS_W: base 1.0; [3,4,5,9,10,11,16,17,18]=2.5; [15,7,12,8]=0.75; [0]=0.5
__constant__ float c_w[NC] = {
    0.5f, 1.0f, 1.0f, 2.5f, 2.5f, 2.5f, 1.0f, 0.75f, 0.75f, 2.5f, 2.5f,
    2.5f, 0.75f, 1.0f, 1.0f, 0.75f, 2.5f, 2.5f, 2.5f, 1.0f, 1.0f};

// ------------- Kernel 1: transposed per-truth argmax, division-free (R17) -------------
__global__ __launch_bounds__(256) void k_argmax(
    const float4* __restrict__ defaults, const float4* __restrict__ gtb,
    float* __restrict__ pbin, float* __restrict__ pbun, int* __restrict__ pbi)
{
    const int b = blockIdx.x, s = blockIdx.y, t = threadIdx.x;
    const int lane = t & 63, wv = t >> 6;
    __shared__ float4 s_def[CH];
    __shared__ float s_t0[NM], s_t1[NM], s_t2[NM], s_t3[NM], s_area[NM];
    __shared__ float s_ri[NM][4], s_ru[NM][4];
    __shared__ int   s_rx[NM][4];

    if (t < NM) {
        float4 g = gtb[b * NM + t];
        s_t0[t] = g.x; s_t1[t] = g.y; s_t2[t] = g.z; s_t3[t] = g.w;
        s_area[t] = (g.z - g.x) * (g.w - g.y);
    }
    const int pbase = s * CH;
    const int cnt = min(NP - pbase, CH);
    for (int i = t; i < cnt; i += 256)
        s_def[i] = defaults[pbase + i];
    __syncthreads();

    const int j = t & 15;
    const int sub = t >> 4;
    const float g0 = s_t0[j], g1 = s_t1[j], g2 = s_t2[j], g3 = s_t3[j], ga = s_area[j];

    float bi = -1.0f, bu = 1.0f; int bx = 0x7fffffff;
    for (int i = sub; i < cnt; i += 16) {        // ascending p: strict > keeps smallest
        float4 d = s_def[i];
        float a1 = (d.z - d.x) * (d.w - d.y);
        float w = fminf(d.z, g2) - fmaxf(d.x, g0);
        float h = fminf(d.w, g3) - fmaxf(d.y, g1);
        w = fmaxf(w, 0.0f); h = fmaxf(h, 0.0f);
        float inter = w * h;
        float uni = a1 + ga - inter;
        if (inter * bu > bi * uni) { bi = inter; bu = uni; bx = pbase + i; }
    }

    #pragma unroll
    for (int off = 16; off <= 32; off <<= 1) {
        float i2 = __shfl_xor(bi, off);
        float u2 = __shfl_xor(bu, off);
        int   x2 = __shfl_xor(bx, off);
        float a = i2 * bu, c = bi * u2;
        if (a > c || (a == c && x2 < bx)) { bi = i2; bu = u2; bx = x2; }
    }
    if (lane < NM) { s_ri[lane][wv] = bi; s_ru[lane][wv] = bu; s_rx[lane][wv] = bx; }
    __syncthreads();
    if (t < NM) {
        float vi = s_ri[t][0], vu = s_ru[t][0]; int x = s_rx[t][0];
        #pragma unroll
        for (int w = 1; w < 4; w++) {
            float i2 = s_ri[t][w], u2 = s_ru[t][w]; int x2 = s_rx[t][w];
            float a = i2 * vu, c = vi * u2;
            if (a > c || (a == c && x2 < x)) { vi = i2; vu = u2; x = x2; }
        }
        pbin[(b * PSPLIT + s) * NM + t] = vi;
        pbun[(b * PSPLIT + s) * NM + t] = vu;
        pbi [(b * PSPLIT + s) * NM + t] = x;
    }
}

// ------- Kernel 2: fused match-resolve + losses; div-free IoU + no-max softmax (R19) -------
__global__ __launch_bounds__(256) void k_loss(
    const float4* __restrict__ loc, const float* __restrict__ conf,
    const float* __restrict__ cent, const float4* __restrict__ defaults,
    const float4* __restrict__ gtb, const int* __restrict__ gtl,
    const float* __restrict__ pbin, const float* __restrict__ pbun,
    const int* __restrict__ pbi,
    float* __restrict__ lossc,
    int* __restrict__ nposP, float* __restrict__ locP,
    float* __restrict__ centP, float* __restrict__ pfocP)
{
    const int b = blockIdx.x, s = blockIdx.y, t = threadIdx.x;
    __shared__ float s_t0[NM], s_t1[NM], s_t2[NM], s_t3[NM], s_area[NM];
    __shared__ int s_lab[NM], s_ovp[NM];
    if (t < NM) {
        float4 g = gtb[b * NM + t];
        s_t0[t] = g.x; s_t1[t] = g.y; s_t2[t] = g.z; s_t3[t] = g.w;
        s_area[t] = (g.z - g.x) * (g.w - g.y);
        s_lab[t] = gtl[b * NM + t];
        float vi = -2.0f, vu = 1.0f; int x = 0x7fffffff;
        for (int c = 0; c < PSPLIT; c++) {
            float i2 = pbin[(b * PSPLIT + c) * NM + t];
            float u2 = pbun[(b * PSPLIT + c) * NM + t];
            int   x2 = pbi [(b * PSPLIT + c) * NM + t];
            float a = i2 * vu, cc = vi * u2;
            if (a > cc || (a == cc && x2 < x)) { vi = i2; vu = u2; x = x2; }
        }
        s_ovp[t] = x;
    }
    __syncthreads();

    float locS = 0.0f, centS = 0.0f, pfocS = 0.0f; int np = 0;

    const int p = s * 256 + t;
    if (p < NP) {
        const float* cp = conf + ((size_t)b * NP + p) * NC;
        f32x4 v0 = *(const f32x4*)(cp + 0);
        f32x4 v1 = *(const f32x4*)(cp + 4);
        f32x4 v2 = *(const f32x4*)(cp + 8);
        f32x4 v3 = *(const f32x4*)(cp + 12);
        f32x4 v4 = *(const f32x4*)(cp + 16);
        float c20 = cp[20];

        float4 d = defaults[p];
        float a1 = (d.z - d.x) * (d.w - d.y);
        float bi = -1.0f, bu = 1.0f; int bj = 0;
        #pragma unroll
        for (int j = 0; j < NM; j++) {
            float w2 = fminf(d.z, s_t2[j]) - fmaxf(d.x, s_t0[j]);
            float h2 = fminf(d.w, s_t3[j]) - fmaxf(d.y, s_t1[j]);
            w2 = fmaxf(w2, 0.0f); h2 = fmaxf(h2, 0.0f);
            float inter = w2 * h2;
            float uni = a1 + s_area[j] - inter;
            if (inter * bu > bi * uni) { bi = inter; bu = uni; bj = j; }  // first-occurrence
        }
        bool ovr = false;
        #pragma unroll
        for (int j = NM - 1; j >= 0; j--) {       // later j wins (ref override loop)
            if (s_ovp[j] == p) { bj = j; ovr = true; break; }
        }
        int lab = (!ovr && 2.0f * bi < bu) ? 0 : s_lab[bj];
        bool pos = lab > 0;

        float se = __expf(v0.x) + __expf(v0.y) + __expf(v0.z) + __expf(v0.w)
                 + __expf(v1.x) + __expf(v1.y) + __expf(v1.z) + __expf(v1.w)
                 + __expf(v2.x) + __expf(v2.y) + __expf(v2.z) + __expf(v2.w)
                 + __expf(v3.x) + __expf(v3.y) + __expf(v3.z) + __expf(v3.w)
                 + __expf(v4.x) + __expf(v4.y) + __expf(v4.z) + __expf(v4.w)
                 + __expf(c20);
        f32x4 va = (lab < 8) ? ((lab < 4) ? v0 : v1)
                             : ((lab < 12) ? v2 : ((lab < 16) ? v3 : v4));
        int li = lab & 3;
        float cl = (li < 2) ? ((li == 0) ? va.x : va.y) : ((li == 2) ? va.z : va.w);
        cl = (lab == 20) ? c20 : cl;

        float logpt = cl - __logf(se);
        float ce = -logpt;
        float pt = __expf(logpt);
        float omp = 1.0f - pt;
        float focal = 0.25f * omp * omp * c_w[lab] * ce;

        lossc[(size_t)b * NP + p] = pos ? 0.0f : focal;

        if (pos) {
            float g0 = s_t0[bj], g1 = s_t1[bj], g2 = s_t2[bj], g3 = s_t3[bj];
            float dw = d.z - d.x, dh = d.w - d.y;
            float gw = g2 - g0,  gh = g3 - g1;
            float dcx = d.x + dw * 0.5f, dcy = d.y + dh * 0.5f;
            float gcx = g0 + gw * 0.5f,  gcy = g1 + gh * 0.5f;
            float e0 = (gcx - dcx) / (dw * 0.1f + 1e-8f);
            float e1 = (gcy - dcy) / (dh * 0.1f + 1e-8f);
            float e2 = logf(gw / (dw + 1e-8f) + 1e-8f) / 0.1f;
            float e3 = logf(gh / (dh + 1e-8f) + 1e-8f) / 0.1f;
            float4 lp = loc[(size_t)b * NP + p];
            float a, sl = 0.0f;
            a = fabsf(lp.x - e0); sl += (a < 1.0f) ? 0.5f * a * a : a - 0.5f;
            a = fabsf(lp.y - e1); sl += (a < 1.0f) ? 0.5f * a * a : a - 0.5f;
            a = fabsf(lp.z - e2); sl += (a < 1.0f) ? 0.5f * a * a : a - 0.5f;
            a = fabsf(lp.w - e3); sl += (a < 1.0f) ? 0.5f * a * a : a - 0.5f;
            locS += sl;

            float ccx = (g0 + g2) * 0.5f, ccy = (g1 + g3) * 0.5f;
            float ld = ccx - g0, rd = g2 - ccx, td = ccy - g1, bd = g3 - ccy;
            float centT = sqrtf((fminf(ld, rd) / fmaxf(ld, rd + 1e-8f)) *
                                (fminf(td, bd) / fmaxf(td, bd + 1e-8f)));
            float x = cent[(size_t)b * NP + p];
            float bce = fmaxf(x, 0.0f) - x * centT + log1pf(expf(-fabsf(x)));
            centS += bce;
            pfocS += focal;
            np++;
        }
    }

    const int lane = t & 63, wv = t >> 6;
    float fnp = (float)np;
    #pragma unroll
    for (int off = 32; off > 0; off >>= 1) {
        locS  += __shfl_down(locS,  off);
        centS += __shfl_down(centS, off);
        pfocS += __shfl_down(pfocS, off);
        fnp   += __shfl_down(fnp,   off);
    }
    __shared__ float r0[4], r1[4], r2[4], r3[4];
    if (lane == 0) { r0[wv] = locS; r1[wv] = centS; r2[wv] = pfocS; r3[wv] = fnp; }
    __syncthreads();
    if (t == 0) {
        int idx = b * SSPL + s;
        locP[idx]  = r0[0] + r0[1] + r0[2] + r0[3];
        centP[idx] = r1[0] + r1[1] + r1[2] + r1[3];
        pfocP[idx] = r2[0] + r2[1] + r2[2] + r2[3];
        nposP[idx] = (int)(r3[0] + r3[1] + r3[2] + r3[3]);
    }
}

// ------- Kernel 3: per-batch top-k via 2-pass {11,11}-bit histogram select (R21) -------
// vk resolves bits [10,32); boundary-bin keys approximated at the bin floor via the
// (k - cgt)*vk correction — relative error 2^-13, final-scalar error ~1e-4 << 0.25 thr.
__global__ __launch_bounds__(512) void k_topk(
    const float* __restrict__ lossc, const int* __restrict__ nposP,
    const float* __restrict__ locP, const float* __restrict__ centP,
    const float* __restrict__ pfocP,
    float* __restrict__ locB, float* __restrict__ centB, float* __restrict__ pfocB,
    int* __restrict__ nposB, float* __restrict__ topkB, float* __restrict__ selcB)
{
    const int b = blockIdx.x, t = threadIdx.x;
    const int lane = t & 63, wv8 = t >> 6;   // 8 waves
    __shared__ unsigned s_hist[2048];
    __shared__ unsigned s_ws[8];
    __shared__ unsigned s_selB, s_selC;
    __shared__ float s_pf[3];
    __shared__ unsigned s_npb;
    __shared__ int   s_ci[8];
    __shared__ float s_sf[8];

    unsigned ukey[NKEY2];
    #pragma unroll
    for (int i = 0; i < NKEY2; i++) {
        int p = i * 512 + t;
        ukey[i] = (p < NP) ? __float_as_uint(lossc[(size_t)b * NP + p]) : 0u;
    }

    if (wv8 == 0) {
        float lB = 0.0f, cB = 0.0f, fB = 0.0f; unsigned nB = 0;
        if (lane < SSPL) {
            int i = b * SSPL + lane;
            lB = locP[i]; cB = centP[i]; fB = pfocP[i]; nB = (unsigned)nposP[i];
        }
        #pragma unroll
        for (int off = 32; off > 0; off >>= 1) {
            lB += __shfl_down(lB, off); cB += __shfl_down(cB, off);
            fB += __shfl_down(fB, off); nB += __shfl_down(nB, off);
        }
        if (lane == 0) { s_pf[0] = lB; s_pf[1] = cB; s_pf[2] = fB; s_npb = nB; }
    }
    __syncthreads();
    const int npb = (int)s_npb;
    const int k = min(3 * npb, NP - 1);

    unsigned vk = 0;
    if (k > 0) {
        unsigned carried = 0;
        #pragma unroll
        for (int pass = 0; pass < 2; pass++) {
            const int lo = (pass == 0) ? 21 : 10;   // bits [21,32), then [10,21)
            const unsigned himask = (pass == 0) ? 0u : (0xFFFFFFFFu << 21);

            for (int z = t; z < 2048; z += 512) s_hist[z] = 0;
            __syncthreads();

            #pragma unroll
            for (int i = 0; i < NKEY2; i++) {
                unsigned kk = ukey[i];
                if ((kk & himask) == (vk & himask))
                    atomicAdd(&s_hist[(kk >> lo) & 2047], 1u);
            }
            __syncthreads();

            unsigned h[4]; unsigned tot = 0;
            #pragma unroll
            for (int j = 0; j < 4; j++) {
                h[j] = s_hist[t * 4 + j];
                tot += h[j];
            }
            unsigned suf = tot;   // inclusive suffix within wave
            #pragma unroll
            for (int off = 1; off < 64; off <<= 1) {
                unsigned o = __shfl_down(suf, off);
                if (lane + off < 64) suf += o;
            }
            if (lane == 0) s_ws[wv8] = suf;
            __syncthreads();
            unsigned aw = 0;
            for (int w = wv8 + 1; w < 8; w++) aw += s_ws[w];
            unsigned acc = aw + (suf - tot);   // count strictly above my chunk's top bin
            #pragma unroll
            for (int j = 3; j >= 0; j--) {
                if (carried + acc < (unsigned)k &&
                    (unsigned)k <= carried + acc + h[j]) {
                    s_selB = (unsigned)(t * 4 + j);
                    s_selC = carried + acc;
                }
                acc += h[j];
            }
            __syncthreads();
            vk |= s_selB << lo;
            carried = s_selC;
            __syncthreads();
        }
    }

    // sum/count of keys strictly greater than vk (bin floor); correction term
    // (k - cgt)*vk handles boundary-bin keys at 2^-13 relative accuracy.
    int cgt = 0; float sgt = 0.0f;
    #pragma unroll
    for (int i = 0; i < NKEY2; i++) {
        unsigned kk = ukey[i];
        if (kk > vk) { cgt++; sgt += __uint_as_float(kk); }
    }
    #pragma unroll
    for (int off = 32; off > 0; off >>= 1) {
        cgt += __shfl_down(cgt, off);
        sgt += __shfl_down(sgt, off);
    }
    if (lane == 0) { s_ci[wv8] = cgt; s_sf[wv8] = sgt; }
    __syncthreads();
    if (t == 0) {
        int tc = 0; float ts = 0.0f;
        #pragma unroll
        for (int w = 0; w < 8; w++) { tc += s_ci[w]; ts += s_sf[w]; }
        locB[b] = s_pf[0]; centB[b] = s_pf[1]; pfocB[b] = s_pf[2];
        nposB[b] = npb;
        topkB[b] = (k > 0) ? (ts + (float)(k - tc) * __uint_as_float(vk)) : 0.0f;
        selcB[b] = (float)(npb + k);
    }
}

// ---------------- Kernel 4: final combine ----------------
__global__ __launch_bounds__(64) void k_final(
    const float* __restrict__ locB, const float* __restrict__ centB,
    const float* __restrict__ pfocB, const int* __restrict__ nposB,
    const float* __restrict__ topkB, const float* __restrict__ selcB,
    float* __restrict__ out)
{
    const int t = threadIdx.x;
    float l = locB[t], c = centB[t], pf = pfocB[t];
    float npf = (float)nposB[t], tk = topkB[t], sc = selcB[t];
    #pragma unroll
    for (int off = 32; off > 0; off >>= 1) {
        l   += __shfl_down(l,   off);
        c   += __shfl_down(c,   off);
        pf  += __shfl_down(pf,  off);
        npf += __shfl_down(npf, off);
        tk  += __shfl_down(tk,  off);
        sc  += __shfl_down(sc,  off);
    }
    if (t == 0)
        out[0] = 2.0f * (l / npf) + (pf + tk) / sc + (c / npf);
}

extern "C" void kernel_launch(void* const* d_in, const int* in_sizes, int n_in,
                              void* d_out, int out_size, void* d_ws, size_t ws_size,
                              hipStream_t stream) {
    const float4* loc      = (const float4*)d_in[0];
    const float*  conf     = (const float*)d_in[1];
    const float*  cent     = (const float*)d_in[2];
    const float4* defaults = (const float4*)d_in[3];
    const float4* gtb      = (const float4*)d_in[4];
    const int*    gtl      = (const int*)d_in[5];
    float* out = (float*)d_out;

    const size_t BP = (size_t)NB * NP;
    const int NT = NB * SSPL;   // 2240 loss tiles
    char* q = (char*)d_ws;
    float* lossc = (float*)q;  q += BP * 4;
    int*   nposP = (int*)q;    q += NT * 4;
    float* locP  = (float*)q;  q += NT * 4;
    float* centP = (float*)q;  q += NT * 4;
    float* pfocP = (float*)q;  q += NT * 4;
    float* locB  = (float*)q;  q += NB * 4;
    float* centB = (float*)q;  q += NB * 4;
    float* pfocB = (float*)q;  q += NB * 4;
    int*   nposB = (int*)q;    q += NB * 4;
    float* topkB = (float*)q;  q += NB * 4;
    float* selcB = (float*)q;  q += NB * 4;
    float* pbin  = (float*)q;  q += (size_t)NB * PSPLIT * NM * 4;
    float* pbun  = (float*)q;  q += (size_t)NB * PSPLIT * NM * 4;
    int*   pbi   = (int*)q;

    k_argmax<<<dim3(NB, PSPLIT), 256, 0, stream>>>(defaults, gtb, pbin, pbun, pbi);
    k_loss<<<dim3(NB, SSPL), 256, 0, stream>>>(loc, conf, cent, defaults, gtb, gtl,
                                               pbin, pbun, pbi, lossc,
                                               nposP, locP, centP, pfocP);
    k_topk<<<NB, 512, 0, stream>>>(lossc, nposP, locP, centP, pfocP,
                                   locB, centB, pfocB, nposB, topkB, selcB);
    k_final<<<1, 64, 0, stream>>>(locB, centB, pfocB, nposB, topkB, selcB, out);
}